// Round 9
// baseline (1930.622 us; speedup 1.0000x reference)
//
#include <hip/hip_runtime.h>
#include <hip/hip_bf16.h>

#define T_TOKENS 16384
#define HID 1024
#define NEXP 8
#define INTER 3584
#define PAIRS (2*T_TOKENS)
#define PAD_MAX (PAIRS + NEXP*128)   // 33792, multiple of 128

using f32x4    = __attribute__((ext_vector_type(4))) float;
using bfrag    = __attribute__((ext_vector_type(8))) short;
using float4_t = __attribute__((ext_vector_type(4))) float;
using ushort8_t = __attribute__((ext_vector_type(8))) unsigned short;

__device__ inline unsigned short f2bf(float f){
    unsigned u = __float_as_uint(f);
    u += 0x7FFFu + ((u >> 16) & 1u);          // RNE
    return (unsigned short)(u >> 16);
}

// async global -> LDS, 16B per lane, dest = wave base + lane*16 (linear)
__device__ inline void gload16(const unsigned short* g, unsigned short* l){
    __builtin_amdgcn_global_load_lds(
        (const __attribute__((address_space(1))) void*)g,
        (__attribute__((address_space(3))) void*)l, 16, 0, 0);
}

// counted-vmcnt phase barriers (soundness proven per-schedule, see K-loop comments)
#define BAR_VM2() asm volatile("s_waitcnt vmcnt(2)\n\ts_barrier" ::: "memory")
#define BAR_VM4() asm volatile("s_waitcnt vmcnt(4)\n\ts_barrier" ::: "memory")
#define BAR_VM0() asm volatile("s_waitcnt vmcnt(0)\n\ts_barrier" ::: "memory")

// bijective XCD swizzle (m204)
__device__ inline int xcd_swz(int flat, int nwg){
    int q = nwg >> 3, r = nwg & 7;
    int xcd = flat & 7, idx = flat >> 3;
    return (xcd < r ? xcd*(q+1) : r*(q+1) + (xcd - r)*q) + idx;
}

// supertile decode: contiguous sw chunk keeps STM M-tiles L2-resident across panels
__device__ inline void st_decode(int sw, int nM, int nP, int STM,
                                 int& mt, int& p){
    int stSize = STM * nP;
    int st = sw / stSize;
    int rem = sw - st * stSize;
    int base = st * STM;
    int stM = (base + STM <= nM) ? STM : (nM - base);
    p  = rem / stM;
    mt = base + (rem - p * stM);
}

// ---------------- f32 -> bf16 conversion for the 3 weight tensors ----------------
__global__ __launch_bounds__(256) void conv3_kernel(
    const float* __restrict__ w1, const float* __restrict__ w3,
    const float* __restrict__ w2,
    unsigned short* __restrict__ w1b, unsigned short* __restrict__ w3b,
    unsigned short* __restrict__ w2b)
{
    const int n = NEXP * INTER * HID;
    const float* in = (blockIdx.y == 0) ? w1 : (blockIdx.y == 1) ? w3 : w2;
    unsigned short* out = (blockIdx.y == 0) ? w1b : (blockIdx.y == 1) ? w3b : w2b;
    int i0 = (blockIdx.x * 256 + threadIdx.x) * 8;
    int stride = gridDim.x * 256 * 8;
    for (int i = i0; i < n; i += stride){
        float4_t a = *reinterpret_cast<const float4_t*>(in + i);
        float4_t b = *reinterpret_cast<const float4_t*>(in + i + 4);
        ushort8_t o;
        o[0]=f2bf(a.x); o[1]=f2bf(a.y); o[2]=f2bf(a.z); o[3]=f2bf(a.w);
        o[4]=f2bf(b.x); o[5]=f2bf(b.y); o[6]=f2bf(b.z); o[7]=f2bf(b.w);
        *reinterpret_cast<ushort8_t*>(out + i) = o;
    }
}

// ---------------- router (+ fused x->bf16 conversion) ----------------
__global__ __launch_bounds__(256) void router_kernel(
    const float* __restrict__ x, const float* __restrict__ gw,
    int* __restrict__ topk_idx, float* __restrict__ topk_w,
    unsigned short* __restrict__ xb)
{
    int wave = threadIdx.x >> 6;
    int lane = threadIdx.x & 63;
    int t = blockIdx.x * 4 + wave;

    float acc[NEXP];
#pragma unroll
    for (int e = 0; e < NEXP; ++e) acc[e] = 0.f;

    const float* xr = x + (size_t)t * HID;
    for (int hb = 0; hb < HID; hb += 64){
        float xv = xr[hb + lane];
#pragma unroll
        for (int e = 0; e < NEXP; ++e)
            acc[e] += xv * gw[e * HID + hb + lane];
    }

    // fused bf16 conversion of this token row
    unsigned short* xbr = xb + (size_t)t * HID;
#pragma unroll
    for (int r = 0; r < 2; ++r){
        int c = (lane + r*64) * 8;
        float4_t va = *reinterpret_cast<const float4_t*>(xr + c);
        float4_t vb = *reinterpret_cast<const float4_t*>(xr + c + 4);
        ushort8_t o;
        o[0]=f2bf(va.x); o[1]=f2bf(va.y); o[2]=f2bf(va.z); o[3]=f2bf(va.w);
        o[4]=f2bf(vb.x); o[5]=f2bf(vb.y); o[6]=f2bf(vb.z); o[7]=f2bf(vb.w);
        *reinterpret_cast<ushort8_t*>(xbr + c) = o;
    }

#pragma unroll
    for (int e = 0; e < NEXP; ++e){
#pragma unroll
        for (int s = 32; s > 0; s >>= 1)
            acc[e] += __shfl_xor(acc[e], s, 64);
    }
    if (lane == 0){
        int e0 = 0; float m0 = acc[0];
#pragma unroll
        for (int e = 1; e < NEXP; ++e) if (acc[e] > m0){ m0 = acc[e]; e0 = e; }
        int e1 = -1; float m1 = -1e30f;
#pragma unroll
        for (int e = 0; e < NEXP; ++e) if (e != e0 && acc[e] > m1){ m1 = acc[e]; e1 = e; }
        float p1 = __expf(m1 - m0);
        float inv = 1.f / (1.f + p1);
        topk_idx[2*t]   = e0;
        topk_idx[2*t+1] = e1;
        topk_w[2*t]   = inv;
        topk_w[2*t+1] = p1 * inv;
    }
}

// ---------------- histogram: LDS-reduced ----------------
__global__ __launch_bounds__(256) void hist_kernel(
    const int* __restrict__ topk_idx, int* __restrict__ counts)
{
    __shared__ int h[NEXP];
    if (threadIdx.x < NEXP) h[threadIdx.x] = 0;
    __syncthreads();
    int i0 = blockIdx.x * 256 + threadIdx.x;
    for (int i = i0; i < PAIRS; i += gridDim.x * 256)
        atomicAdd(&h[topk_idx[i]], 1);
    __syncthreads();
    if (threadIdx.x < NEXP) atomicAdd(&counts[threadIdx.x], h[threadIdx.x]);
}

__global__ void scan_kernel(const int* __restrict__ counts, int* __restrict__ offp)
{
    if (threadIdx.x == 0 && blockIdx.x == 0){
        int s = 0;
        for (int e = 0; e < NEXP; ++e){
            offp[e] = s;
            s += (counts[e] + 127) & ~127;
        }
        offp[NEXP] = s;
    }
}

__global__ __launch_bounds__(128) void padfill_kernel(
    const int* __restrict__ counts, const int* __restrict__ offp,
    int* __restrict__ pair_token, float* __restrict__ pair_w)
{
    int e = blockIdx.x;
    int base = offp[e];
    int aligned = offp[e+1] - base;
    for (int s = counts[e] + threadIdx.x; s < aligned; s += 128){
        pair_token[base + s] = (base + s) & (T_TOKENS - 1);
        pair_w[base + s] = 0.f;
    }
}

// ---------------- scatter: block-batched range reservation ----------------
__global__ __launch_bounds__(256) void scatter_kernel(
    const int* __restrict__ topk_idx, const float* __restrict__ topk_w,
    const int* __restrict__ offp, int* __restrict__ cursors,
    int* __restrict__ pair_token, float* __restrict__ pair_w)
{
    __shared__ int hist[NEXP], base[NEXP], lcur[NEXP];
    int tid = threadIdx.x;
    if (tid < NEXP){ hist[tid] = 0; lcur[tid] = 0; }
    __syncthreads();

    int t = blockIdx.x * 256 + tid;
    int e0 = topk_idx[2*t], e1 = topk_idx[2*t + 1];
    atomicAdd(&hist[e0], 1);
    atomicAdd(&hist[e1], 1);
    __syncthreads();

    if (tid < NEXP) base[tid] = atomicAdd(&cursors[tid], hist[tid]);
    __syncthreads();

    int r0 = atomicAdd(&lcur[e0], 1);
    int r1 = atomicAdd(&lcur[e1], 1);
    int p0 = offp[e0] + base[e0] + r0;
    int p1 = offp[e1] + base[e1] + r1;
    pair_token[p0] = t;  pair_w[p0] = topk_w[2*t];
    pair_token[p1] = t;  pair_w[p1] = topk_w[2*t + 1];
}

// ---------------- fused w1/w3 GEMM + SwiGLU -> act ----------------
// M128 x N64(h&u), BK=64, 2 dbufs. K-loop: 2 sub-phases with counted vmcnt:
//   P0(t): read all a-frags + n=0 b-frags; issue A(t+1); MFMA n=0
//   P1(t): read n=1 b-frags; issue B(t+1) [P0-needed groups first]; MFMA n=1
// Waits (per-wave, sound): entering P0: outstanding = A(t)4+B(t)4 -> vmcnt(2)
// retires A4 + B-first-2 (exactly P0's reads). Entering P1: outstanding =
// B(t)last2 + A(t+1)4 = 6 -> vmcnt(4) retires B last2. Barriers give
// cross-wave visibility and writer/reader separation (2 barriers between a
// buffer's last read and its overwrite).
__global__ __launch_bounds__(256) void gemm_act_kernel(
    const unsigned short* __restrict__ xb,
    const unsigned short* __restrict__ w1b,
    const unsigned short* __restrict__ w3b,
    const int* __restrict__ offp,
    const int* __restrict__ pair_token, const float* __restrict__ pair_w,
    unsigned short* __restrict__ act, int r0)
{
    int nP = gridDim.x, nM = gridDim.y;
    int sw = xcd_swz(blockIdx.y * nP + blockIdx.x, nP * nM);
    int mt, p;
    st_decode(sw, nM, nP, 8, mt, p);
    int by = mt, bx = p;

    int R = r0 + by * 128;
    if (R >= offp[NEXP]) return;
    int e = 0;
    while (offp[e+1] <= R) ++e;
    int icol0 = bx * 64;

    __shared__ alignas(16) unsigned short As0[128*64], As1[128*64];
    __shared__ alignas(16) unsigned short B10[64*64],  B11[64*64];
    __shared__ alignas(16) unsigned short B30[64*64],  B31[64*64];
    __shared__ int   toks[128];
    __shared__ float pws[128];

    int tid = threadIdx.x;
    if (tid < 128){
        toks[tid] = pair_token[R + tid];
        pws[tid]  = pair_w[R + tid];
    }
    __syncthreads();

    int w = tid >> 6, lane = tid & 63;
    int wm = w >> 1, wn = w & 1;
    int lr = lane >> 3;
    int l15 = lane & 15;
    int swz8 = ((lane & 7) ^ lr) * 8;          // inverse-swizzled source chunk

    size_t asrc[4];
#pragma unroll
    for (int i = 0; i < 4; ++i)
        asrc[i] = (size_t)toks[w*32 + i*8 + lr] * HID + swz8;

    const unsigned short* w1e = w1b + (size_t)e * INTER * HID;
    const unsigned short* w3e = w3b + (size_t)e * INTER * HID;

    // B staging groups: wave w stages first-group rows gf (P0-needed: {0,8,32,40})
    // and second-group rows gf+16 (P1-needed: {16,24,48,56})
    int gf = ((w & 2) * 2 + (w & 1)) * 8;
    size_t bsrcF = (size_t)(icol0 + gf + lr) * HID + swz8;
    size_t bsrcS = (size_t)(icol0 + gf + 16 + lr) * HID + swz8;

    int ccol[2];
#pragma unroll
    for (int kk = 0; kk < 2; ++kk)
        ccol[kk] = (((kk*4 + (lane >> 4)) ^ (lane & 7)) * 8);

    f32x4 acc_h[4][2], acc_u[4][2];
#pragma unroll
    for (int m = 0; m < 4; ++m)
#pragma unroll
        for (int n = 0; n < 2; ++n){
            acc_h[m][n] = (f32x4){0.f,0.f,0.f,0.f};
            acc_u[m][n] = (f32x4){0.f,0.f,0.f,0.f};
        }

    bfrag aF[4][2];   // carried A-frags (read in P0, used in P0+P1)

    auto stageA = [&](unsigned short* Ad, int t){
        int k0 = t * 64;
#pragma unroll
        for (int i = 0; i < 4; ++i) gload16(xb + asrc[i] + k0, Ad + (w*32 + i*8)*64);
    };
    auto stageBfirst = [&](unsigned short* B1d, unsigned short* B3d, int t){
        int k0 = t * 64;
        gload16(w1e + bsrcF + k0, B1d + gf*64);
        gload16(w3e + bsrcF + k0, B3d + gf*64);
    };
    auto stageBsecond = [&](unsigned short* B1d, unsigned short* B3d, int t){
        int k0 = t * 64;
        gload16(w1e + bsrcS + k0, B1d + (gf+16)*64);
        gload16(w3e + bsrcS + k0, B3d + (gf+16)*64);
    };

    auto phase0 = [&](const unsigned short* As, const unsigned short* B1s,
                      const unsigned short* B3s, unsigned short* Ad,
                      bool issue, int tn){
#pragma unroll
        for (int m = 0; m < 4; ++m)
#pragma unroll
            for (int kk = 0; kk < 2; ++kk)
                aF[m][kk] = *reinterpret_cast<const bfrag*>(
                    &As[(wm*64 + m*16 + l15)*64 + ccol[kk]]);
        bfrag b1[2], b3[2];
#pragma unroll
        for (int kk = 0; kk < 2; ++kk){
            b1[kk] = *reinterpret_cast<const bfrag*>(&B1s[(wn*32 + l15)*64 + ccol[kk]]);
            b3[kk] = *reinterpret_cast<const bfrag*>(&B3s[(wn*32 + l15)*64 + ccol[kk]]);
        }
        if (issue) stageA(Ad, tn);
        __builtin_amdgcn_s_setprio(1);
#pragma unroll
        for (int kk = 0; kk < 2; ++kk)
#pragma unroll
            for (int m = 0; m < 4; ++m){
                acc_h[m][0] = __builtin_amdgcn_mfma_f32_16x16x32_bf16(aF[m][kk], b1[kk], acc_h[m][0], 0, 0, 0);
                acc_u[m][0] = __builtin_amdgcn_mfma_f32_16x16x32_bf16(aF[m][kk], b3[kk], acc_u[m][0], 0, 0, 0);
            }
        __builtin_amdgcn_s_setprio(0);
    };

    auto phase1 = [&](const unsigned short* B1s, const unsigned short* B3s,
                      unsigned short* B1d, unsigned short* B3d,
                      bool issue, int tn){
        bfrag b1[2], b3[2];
#pragma unroll
        for (int kk = 0; kk < 2; ++kk){
            b1[kk] = *reinterpret_cast<const bfrag*>(&B1s[(wn*32 + 16 + l15)*64 + ccol[kk]]);
            b3[kk] = *reinterpret_cast<const bfrag*>(&B3s[(wn*32 + 16 + l15)*64 + ccol[kk]]);
        }
        if (issue){
            stageBfirst(B1d, B3d, tn);
            __builtin_amdgcn_sched_barrier(0);   // pin issue order: first pair before second
            stageBsecond(B1d, B3d, tn);
        }
        __builtin_amdgcn_s_setprio(1);
#pragma unroll
        for (int kk = 0; kk < 2; ++kk)
#pragma unroll
            for (int m = 0; m < 4; ++m){
                acc_h[m][1] = __builtin_amdgcn_mfma_f32_16x16x32_bf16(aF[m][kk], b1[kk], acc_h[m][1], 0, 0, 0);
                acc_u[m][1] = __builtin_amdgcn_mfma_f32_16x16x32_bf16(aF[m][kk], b3[kk], acc_u[m][1], 0, 0, 0);
            }
        __builtin_amdgcn_s_setprio(0);
    };

    const int NT = HID / 64;   // 16 (even)
    // prologue: A(0) then B(0) into buf0 (issue order matters for vmcnt math)
    stageA(As0, 0);
    stageBfirst(B10, B30, 0);
    __builtin_amdgcn_sched_barrier(0);
    stageBsecond(B10, B30, 0);

#pragma unroll 1
    for (int t = 0; t < NT - 2; t += 2){
        BAR_VM2();
        phase0(As0, B10, B30, As1, true, t+1);
        BAR_VM4();
        phase1(B10, B30, B11, B31, true, t+1);
        BAR_VM2();
        phase0(As1, B11, B31, As0, true, t+2);
        BAR_VM4();
        phase1(B11, B31, B10, B30, true, t+2);
    }
    // t = NT-2 (buf0), issues NT-1 -> buf1
    BAR_VM2();
    phase0(As0, B10, B30, As1, true, NT-1);
    BAR_VM4();
    phase1(B10, B30, B11, B31, true, NT-1);
    // t = NT-1 (buf1), no issues
    BAR_VM2();
    phase0(As1, B11, B31, nullptr, false, 0);
    BAR_VM0();
    phase1(B11, B31, nullptr, nullptr, false, 0);

    // epilogue: act = pair_w * silu(h) * u  (bf16)
    size_t arow0 = (size_t)(by * 128) * INTER;
#pragma unroll
    for (int m = 0; m < 4; ++m){
#pragma unroll
        for (int n = 0; n < 2; ++n){
#pragma unroll
            for (int j = 0; j < 4; ++j){
                int rl = wm*64 + m*16 + (lane >> 4)*4 + j;
                float h = acc_h[m][n][j];
                float u = acc_u[m][n][j];
                float v = pws[rl] * h * u / (1.f + __expf(-h));
                int ic = icol0 + wn*32 + n*16 + l15;
                act[arow0 + (size_t)rl * INTER + ic] = f2bf(v);
            }
        }
    }
}

// ---------------- down-proj GEMM: out[tok,:] += act[row,:] @ w2[e]^T ----------------
// M128 x N128, BK=64, K=INTER. Same 2-sub-phase counted-vmcnt schedule:
//   P0: all a-frags + b n{0,1}; issue A(t+1); MFMA n{0,1}
//   P1: b n{2,3}; issue B(t+1) [groups s0,s1 first]; MFMA n{2,3}
__global__ __launch_bounds__(256) void gemm2_kernel(
    const unsigned short* __restrict__ act,
    const unsigned short* __restrict__ w2b,
    const int* __restrict__ offp,
    const int* __restrict__ pair_token,
    float* __restrict__ out, int r0)
{
    int nP = gridDim.x, nM = gridDim.y;
    int sw = xcd_swz(blockIdx.y * nP + blockIdx.x, nP * nM);
    int mt, p;
    st_decode(sw, nM, nP, 4, mt, p);
    int by = mt, bx = p;

    int R = r0 + by * 128;
    if (R >= offp[NEXP]) return;
    int e = 0;
    while (offp[e+1] <= R) ++e;
    int h0 = bx * 128;

    __shared__ alignas(16) unsigned short As0[128*64], As1[128*64];
    __shared__ alignas(16) unsigned short Bs0[128*64], Bs1[128*64];
    __shared__ int toks[128];

    int tid = threadIdx.x;
    if (tid < 128) toks[tid] = pair_token[R + tid];
    __syncthreads();

    int w = tid >> 6, lane = tid & 63;
    int wm = w >> 1, wn = w & 1;
    int lr = lane >> 3;
    int l15 = lane & 15;
    int swz8 = ((lane & 7) ^ lr) * 8;

    const unsigned short* w2e = w2b + (size_t)e * HID * INTER;
    size_t arow0 = (size_t)(by * 128) * INTER;

    size_t asrc[4];
#pragma unroll
    for (int i = 0; i < 4; ++i)
        asrc[i] = arow0 + (size_t)(w*32 + i*8 + lr) * INTER + swz8;

    // B staging: wave w groups s0=w, s1=8+w (P0-needed rows 0-31,64-95),
    // s2=4+w, s3=12+w (P1-needed rows 32-63,96-127)
    int gr0 = w*8, gr1 = 64 + w*8, gr2 = 32 + w*8, gr3 = 96 + w*8;
    size_t bsrc0 = (size_t)(h0 + gr0 + lr) * INTER + swz8;
    size_t bsrc1 = (size_t)(h0 + gr1 + lr) * INTER + swz8;
    size_t bsrc2 = (size_t)(h0 + gr2 + lr) * INTER + swz8;
    size_t bsrc3 = (size_t)(h0 + gr3 + lr) * INTER + swz8;

    int ccol[2];
#pragma unroll
    for (int kk = 0; kk < 2; ++kk)
        ccol[kk] = (((kk*4 + (lane >> 4)) ^ (lane & 7)) * 8);

    f32x4 acc[4][4];
#pragma unroll
    for (int m = 0; m < 4; ++m)
#pragma unroll
        for (int n = 0; n < 4; ++n)
            acc[m][n] = (f32x4){0.f,0.f,0.f,0.f};

    bfrag aF[4][2];

    auto stageA = [&](unsigned short* Ad, int t){
        int kc = t * 64;
#pragma unroll
        for (int i = 0; i < 4; ++i) gload16(act + asrc[i] + kc, Ad + (w*32 + i*8)*64);
    };
    auto stageBfirst = [&](unsigned short* Bd, int t){
        int kc = t * 64;
        gload16(w2e + bsrc0 + kc, Bd + gr0*64);
        gload16(w2e + bsrc1 + kc, Bd + gr1*64);
    };
    auto stageBsecond = [&](unsigned short* Bd, int t){
        int kc = t * 64;
        gload16(w2e + bsrc2 + kc, Bd + gr2*64);
        gload16(w2e + bsrc3 + kc, Bd + gr3*64);
    };

    auto phase0 = [&](const unsigned short* As, const unsigned short* Bs,
                      unsigned short* Ad, bool issue, int tn){
#pragma unroll
        for (int m = 0; m < 4; ++m)
#pragma unroll
            for (int kk = 0; kk < 2; ++kk)
                aF[m][kk] = *reinterpret_cast<const bfrag*>(
                    &As[(wm*64 + m*16 + l15)*64 + ccol[kk]]);
        bfrag b[2][2];
#pragma unroll
        for (int n = 0; n < 2; ++n)
#pragma unroll
            for (int kk = 0; kk < 2; ++kk)
                b[n][kk] = *reinterpret_cast<const bfrag*>(
                    &Bs[(wn*64 + n*16 + l15)*64 + ccol[kk]]);
        if (issue) stageA(Ad, tn);
        __builtin_amdgcn_s_setprio(1);
#pragma unroll
        for (int kk = 0; kk < 2; ++kk)
#pragma unroll
            for (int n = 0; n < 2; ++n)
#pragma unroll
                for (int m = 0; m < 4; ++m)
                    acc[m][n] = __builtin_amdgcn_mfma_f32_16x16x32_bf16(aF[m][kk], b[n][kk], acc[m][n], 0, 0, 0);
        __builtin_amdgcn_s_setprio(0);
    };

    auto phase1 = [&](const unsigned short* Bs, unsigned short* Bd,
                      bool issue, int tn){
        bfrag b[2][2];
#pragma unroll
        for (int n = 0; n < 2; ++n)
#pragma unroll
            for (int kk = 0; kk < 2; ++kk)
                b[n][kk] = *reinterpret_cast<const bfrag*>(
                    &Bs[(wn*64 + (n+2)*16 + l15)*64 + ccol[kk]]);
        if (issue){
            stageBfirst(Bd, tn);
            __builtin_amdgcn_sched_barrier(0);
            stageBsecond(Bd, tn);
        }
        __builtin_amdgcn_s_setprio(1);
#pragma unroll
        for (int kk = 0; kk < 2; ++kk)
#pragma unroll
            for (int n = 0; n < 2; ++n)
#pragma unroll
                for (int m = 0; m < 4; ++m)
                    acc[m][n+2] = __builtin_amdgcn_mfma_f32_16x16x32_bf16(aF[m][kk], b[n][kk], acc[m][n+2], 0, 0, 0);
        __builtin_amdgcn_s_setprio(0);
    };

    const int NT = INTER / 64;   // 56 (even)
    stageA(As0, 0);
    stageBfirst(Bs0, 0);
    __builtin_amdgcn_sched_barrier(0);
    stageBsecond(Bs0, 0);

#pragma unroll 1
    for (int t = 0; t < NT - 2; t += 2){
        BAR_VM2();
        phase0(As0, Bs0, As1, true, t+1);
        BAR_VM4();
        phase1(Bs0, Bs1, true, t+1);
        BAR_VM2();
        phase0(As1, Bs1, As0, true, t+2);
        BAR_VM4();
        phase1(Bs1, Bs0, true, t+2);
    }
    BAR_VM2();
    phase0(As0, Bs0, As1, true, NT-1);
    BAR_VM4();
    phase1(Bs0, Bs1, true, NT-1);
    BAR_VM2();
    phase0(As1, Bs1, nullptr, false, 0);
    BAR_VM0();
    phase1(Bs1, nullptr, false, 0);

#pragma unroll
    for (int m = 0; m < 4; ++m){
#pragma unroll
        for (int n = 0; n < 4; ++n){
#pragma unroll
            for (int j = 0; j < 4; ++j){
                int rl = wm*64 + m*16 + (lane >> 4)*4 + j;
                int hc = h0 + wn*64 + n*16 + l15;
                atomicAdd(&out[(size_t)toks[rl] * HID + hc], acc[m][n][j]);
            }
        }
    }
}

extern "C" void kernel_launch(void* const* d_in, const int* in_sizes, int n_in,
                              void* d_out, int out_size, void* d_ws, size_t ws_size,
                              hipStream_t stream)
{
    const float* x  = (const float*)d_in[0];
    const float* gw = (const float*)d_in[1];
    const float* w1 = (const float*)d_in[2];
    const float* w3 = (const float*)d_in[3];
    const float* w2 = (const float*)d_in[4];
    float* out = (float*)d_out;

    char* ws = (char*)d_ws;
    size_t off = 0;
    auto bump = [&](size_t bytes) -> void* {
        void* p = ws + off;
        off = (off + bytes + 255) & ~(size_t)255;
        return p;
    };
    int*   counts     = (int*)bump(32);
    int*   cursors    = (int*)bump(32);
    int*   offp       = (int*)bump(64);
    int*   topk_idx   = (int*)bump((size_t)PAIRS * 4);
    float* topk_w     = (float*)bump((size_t)PAIRS * 4);
    int*   pair_token = (int*)bump((size_t)PAD_MAX * 4);
    float* pair_w     = (float*)bump((size_t)PAD_MAX * 4);
    unsigned short* xb  = (unsigned short*)bump((size_t)T_TOKENS * HID * 2);
    unsigned short* w1b = (unsigned short*)bump((size_t)NEXP * INTER * HID * 2);
    unsigned short* w3b = (unsigned short*)bump((size_t)NEXP * INTER * HID * 2);
    unsigned short* w2b = (unsigned short*)bump((size_t)NEXP * HID * INTER * 2);
    unsigned short* act = (unsigned short*)(ws + off);

    size_t rem = (ws_size > off) ? (ws_size - off) : 0;
    int RC = (int)(rem / ((size_t)INTER * 2));
    RC &= ~127;
    if (RC > PAD_MAX) RC = PAD_MAX;
    if (RC < 128) RC = 128;
    int nchunks = (PAD_MAX + RC - 1) / RC;

    hipMemsetAsync(d_out, 0, (size_t)T_TOKENS * HID * 4, stream);
    hipMemsetAsync(ws, 0, 1024, stream);

    conv3_kernel<<<dim3(768, 3), 256, 0, stream>>>(w1, w3, w2, w1b, w3b, w2b);

    router_kernel<<<T_TOKENS/4, 256, 0, stream>>>(x, gw, topk_idx, topk_w, xb);
    hist_kernel<<<64, 256, 0, stream>>>(topk_idx, counts);
    scan_kernel<<<1, 64, 0, stream>>>(counts, offp);
    padfill_kernel<<<NEXP, 128, 0, stream>>>(counts, offp, pair_token, pair_w);
    scatter_kernel<<<T_TOKENS/256, 256, 0, stream>>>(topk_idx, topk_w, offp, cursors,
                                                     pair_token, pair_w);

    for (int c = 0; c < nchunks; ++c){
        int r0 = c * RC;
        gemm_act_kernel<<<dim3(INTER/64, RC/128), 256, 0, stream>>>(
            xb, w1b, w3b, offp, pair_token, pair_w, act, r0);
        gemm2_kernel<<<dim3(HID/128, RC/128), 256, 0, stream>>>(
            act, w2b, offp, pair_token, out, r0);
    }
}

// Round 10
// 1056.968 us; speedup vs baseline: 1.8266x; 1.8266x over previous
//
#include <hip/hip_runtime.h>
#include <hip/hip_bf16.h>

#define T_TOKENS 16384
#define HID 1024
#define NEXP 8
#define INTER 3584
#define PAIRS (2*T_TOKENS)
#define PAD_MAX (PAIRS + NEXP*128)   // 33792, multiple of 128

using f32x4    = __attribute__((ext_vector_type(4))) float;
using bfrag    = __attribute__((ext_vector_type(8))) short;
using float4_t = __attribute__((ext_vector_type(4))) float;
using ushort8_t = __attribute__((ext_vector_type(8))) unsigned short;

__device__ inline unsigned short f2bf(float f){
    unsigned u = __float_as_uint(f);
    u += 0x7FFFu + ((u >> 16) & 1u);          // RNE
    return (unsigned short)(u >> 16);
}

// async global -> LDS, 16B per lane, dest = wave base + lane*16 (linear)
__device__ inline void gload16(const unsigned short* g, unsigned short* l){
    __builtin_amdgcn_global_load_lds(
        (const __attribute__((address_space(1))) void*)g,
        (__attribute__((address_space(3))) void*)l, 16, 0, 0);
}

// barrier with counted vmcnt: my oldest 8 staging loads done, newer 8 stay in flight
#define BAR_VM8() asm volatile("s_waitcnt vmcnt(8)\n\ts_barrier" ::: "memory")
#define BAR_VM0() asm volatile("s_waitcnt vmcnt(0)\n\ts_barrier" ::: "memory")
#define BAR_PLAIN() asm volatile("s_barrier" ::: "memory")

// bijective XCD swizzle (m204)
__device__ inline int xcd_swz(int flat, int nwg){
    int q = nwg >> 3, r = nwg & 7;
    int xcd = flat & 7, idx = flat >> 3;
    return (xcd < r ? xcd*(q+1) : r*(q+1) + (xcd - r)*q) + idx;
}

// supertile decode: contiguous sw chunk keeps STM M-tiles L2-resident across panels
__device__ inline void st_decode(int sw, int nM, int nP, int STM,
                                 int& mt, int& p){
    int stSize = STM * nP;
    int st = sw / stSize;
    int rem = sw - st * stSize;
    int base = st * STM;
    int stM = (base + STM <= nM) ? STM : (nM - base);
    p  = rem / stM;
    mt = base + (rem - p * stM);
}

// ---------------- f32 -> bf16 conversion for the 3 weight tensors ----------------
__global__ __launch_bounds__(256) void conv3_kernel(
    const float* __restrict__ w1, const float* __restrict__ w3,
    const float* __restrict__ w2,
    unsigned short* __restrict__ w1b, unsigned short* __restrict__ w3b,
    unsigned short* __restrict__ w2b)
{
    const int n = NEXP * INTER * HID;
    const float* in = (blockIdx.y == 0) ? w1 : (blockIdx.y == 1) ? w3 : w2;
    unsigned short* out = (blockIdx.y == 0) ? w1b : (blockIdx.y == 1) ? w3b : w2b;
    int i0 = (blockIdx.x * 256 + threadIdx.x) * 8;
    int stride = gridDim.x * 256 * 8;
    for (int i = i0; i < n; i += stride){
        float4_t a = *reinterpret_cast<const float4_t*>(in + i);
        float4_t b = *reinterpret_cast<const float4_t*>(in + i + 4);
        ushort8_t o;
        o[0]=f2bf(a.x); o[1]=f2bf(a.y); o[2]=f2bf(a.z); o[3]=f2bf(a.w);
        o[4]=f2bf(b.x); o[5]=f2bf(b.y); o[6]=f2bf(b.z); o[7]=f2bf(b.w);
        *reinterpret_cast<ushort8_t*>(out + i) = o;
    }
}

// ---------------- router (+ fused x->bf16 conversion) ----------------
__global__ __launch_bounds__(256) void router_kernel(
    const float* __restrict__ x, const float* __restrict__ gw,
    int* __restrict__ topk_idx, float* __restrict__ topk_w,
    unsigned short* __restrict__ xb)
{
    int wave = threadIdx.x >> 6;
    int lane = threadIdx.x & 63;
    int t = blockIdx.x * 4 + wave;

    float acc[NEXP];
#pragma unroll
    for (int e = 0; e < NEXP; ++e) acc[e] = 0.f;

    const float* xr = x + (size_t)t * HID;
    for (int hb = 0; hb < HID; hb += 64){
        float xv = xr[hb + lane];
#pragma unroll
        for (int e = 0; e < NEXP; ++e)
            acc[e] += xv * gw[e * HID + hb + lane];
    }

    // fused bf16 conversion of this token row
    unsigned short* xbr = xb + (size_t)t * HID;
#pragma unroll
    for (int r = 0; r < 2; ++r){
        int c = (lane + r*64) * 8;
        float4_t va = *reinterpret_cast<const float4_t*>(xr + c);
        float4_t vb = *reinterpret_cast<const float4_t*>(xr + c + 4);
        ushort8_t o;
        o[0]=f2bf(va.x); o[1]=f2bf(va.y); o[2]=f2bf(va.z); o[3]=f2bf(va.w);
        o[4]=f2bf(vb.x); o[5]=f2bf(vb.y); o[6]=f2bf(vb.z); o[7]=f2bf(vb.w);
        *reinterpret_cast<ushort8_t*>(xbr + c) = o;
    }

#pragma unroll
    for (int e = 0; e < NEXP; ++e){
#pragma unroll
        for (int s = 32; s > 0; s >>= 1)
            acc[e] += __shfl_xor(acc[e], s, 64);
    }
    if (lane == 0){
        int e0 = 0; float m0 = acc[0];
#pragma unroll
        for (int e = 1; e < NEXP; ++e) if (acc[e] > m0){ m0 = acc[e]; e0 = e; }
        int e1 = -1; float m1 = -1e30f;
#pragma unroll
        for (int e = 0; e < NEXP; ++e) if (e != e0 && acc[e] > m1){ m1 = acc[e]; e1 = e; }
        float p1 = __expf(m1 - m0);
        float inv = 1.f / (1.f + p1);
        topk_idx[2*t]   = e0;
        topk_idx[2*t+1] = e1;
        topk_w[2*t]   = inv;
        topk_w[2*t+1] = p1 * inv;
    }
}

// ---------------- histogram: LDS-reduced ----------------
__global__ __launch_bounds__(256) void hist_kernel(
    const int* __restrict__ topk_idx, int* __restrict__ counts)
{
    __shared__ int h[NEXP];
    if (threadIdx.x < NEXP) h[threadIdx.x] = 0;
    __syncthreads();
    int i0 = blockIdx.x * 256 + threadIdx.x;
    for (int i = i0; i < PAIRS; i += gridDim.x * 256)
        atomicAdd(&h[topk_idx[i]], 1);
    __syncthreads();
    if (threadIdx.x < NEXP) atomicAdd(&counts[threadIdx.x], h[threadIdx.x]);
}

__global__ void scan_kernel(const int* __restrict__ counts, int* __restrict__ offp)
{
    if (threadIdx.x == 0 && blockIdx.x == 0){
        int s = 0;
        for (int e = 0; e < NEXP; ++e){
            offp[e] = s;
            s += (counts[e] + 127) & ~127;
        }
        offp[NEXP] = s;
    }
}

__global__ __launch_bounds__(128) void padfill_kernel(
    const int* __restrict__ counts, const int* __restrict__ offp,
    int* __restrict__ pair_token, float* __restrict__ pair_w)
{
    int e = blockIdx.x;
    int base = offp[e];
    int aligned = offp[e+1] - base;
    for (int s = counts[e] + threadIdx.x; s < aligned; s += 128){
        pair_token[base + s] = (base + s) & (T_TOKENS - 1);
        pair_w[base + s] = 0.f;
    }
}

// ---------------- scatter: block-batched range reservation ----------------
__global__ __launch_bounds__(256) void scatter_kernel(
    const int* __restrict__ topk_idx, const float* __restrict__ topk_w,
    const int* __restrict__ offp, int* __restrict__ cursors,
    int* __restrict__ pair_token, float* __restrict__ pair_w)
{
    __shared__ int hist[NEXP], base[NEXP], lcur[NEXP];
    int tid = threadIdx.x;
    if (tid < NEXP){ hist[tid] = 0; lcur[tid] = 0; }
    __syncthreads();

    int t = blockIdx.x * 256 + tid;
    int e0 = topk_idx[2*t], e1 = topk_idx[2*t + 1];
    atomicAdd(&hist[e0], 1);
    atomicAdd(&hist[e1], 1);
    __syncthreads();

    if (tid < NEXP) base[tid] = atomicAdd(&cursors[tid], hist[tid]);
    __syncthreads();

    int r0 = atomicAdd(&lcur[e0], 1);
    int r1 = atomicAdd(&lcur[e1], 1);
    int p0 = offp[e0] + base[e0] + r0;
    int p1 = offp[e1] + base[e1] + r1;
    pair_token[p0] = t;  pair_w[p0] = topk_w[2*t];
    pair_token[p1] = t;  pair_w[p1] = topk_w[2*t + 1];
}

// ---------------- fused w1/w3 GEMM + SwiGLU -> act (bf16) ----------------
// M 128 x N 64 (h & u), BK=64, double-buffered, counted vmcnt, swizzled LDS,
// L2 supertile: 8 M-tiles resident across all panels  [round-8 proven structure]
__global__ __launch_bounds__(256) void gemm_act_kernel(
    const unsigned short* __restrict__ xb,
    const unsigned short* __restrict__ w1b,
    const unsigned short* __restrict__ w3b,
    const int* __restrict__ offp,
    const int* __restrict__ pair_token, const float* __restrict__ pair_w,
    unsigned short* __restrict__ act, int r0)
{
    int nP = gridDim.x, nM = gridDim.y;
    int sw = xcd_swz(blockIdx.y * nP + blockIdx.x, nP * nM);
    int mt, p;
    st_decode(sw, nM, nP, 8, mt, p);
    int by = mt, bx = p;

    int R = r0 + by * 128;
    if (R >= offp[NEXP]) return;
    int e = 0;
    while (offp[e+1] <= R) ++e;
    int icol0 = bx * 64;

    __shared__ alignas(16) unsigned short As0[128*64], As1[128*64];
    __shared__ alignas(16) unsigned short B10[64*64],  B11[64*64];
    __shared__ alignas(16) unsigned short B30[64*64],  B31[64*64];
    __shared__ int   toks[128];
    __shared__ float pws[128];

    int tid = threadIdx.x;
    if (tid < 128){
        toks[tid] = pair_token[R + tid];
        pws[tid]  = pair_w[R + tid];
    }
    __syncthreads();

    int w = tid >> 6, lane = tid & 63;
    int wm = w >> 1, wn = w & 1;
    int lr = lane >> 3;
    int l15 = lane & 15;
    int swz8 = ((lane & 7) ^ lr) * 8;          // inverse-swizzled source chunk

    size_t asrc[4];
#pragma unroll
    for (int i = 0; i < 4; ++i)
        asrc[i] = (size_t)toks[w*32 + i*8 + lr] * HID + swz8;

    const unsigned short* w1e = w1b + (size_t)e * INTER * HID;
    const unsigned short* w3e = w3b + (size_t)e * INTER * HID;
    size_t bsrc[2];
#pragma unroll
    for (int i = 0; i < 2; ++i)
        bsrc[i] = (size_t)(icol0 + w*16 + i*8 + lr) * HID + swz8;

    // swizzled read columns (shorts): ((kk*4 + lane>>4) ^ (row&7)) * 8, row&7 == lane&7
    int ccol[2];
#pragma unroll
    for (int kk = 0; kk < 2; ++kk)
        ccol[kk] = (((kk*4 + (lane >> 4)) ^ (lane & 7)) * 8);

    f32x4 acc_h[4][2], acc_u[4][2];
#pragma unroll
    for (int m = 0; m < 4; ++m)
#pragma unroll
        for (int n = 0; n < 2; ++n){
            acc_h[m][n] = (f32x4){0.f,0.f,0.f,0.f};
            acc_u[m][n] = (f32x4){0.f,0.f,0.f,0.f};
        }

    // exactly 8 gload16 per thread per stage
    auto stageT = [&](unsigned short* As, unsigned short* B1s, unsigned short* B3s, int t){
        int k0 = t * 64;
#pragma unroll
        for (int i = 0; i < 4; ++i) gload16(xb  + asrc[i] + k0, As  + (w*32 + i*8)*64);
#pragma unroll
        for (int i = 0; i < 2; ++i) gload16(w1e + bsrc[i] + k0, B1s + (w*16 + i*8)*64);
#pragma unroll
        for (int i = 0; i < 2; ++i) gload16(w3e + bsrc[i] + k0, B3s + (w*16 + i*8)*64);
    };

    auto computeT = [&](const unsigned short* As, const unsigned short* B1s, const unsigned short* B3s){
        __builtin_amdgcn_s_setprio(1);
#pragma unroll
        for (int kk = 0; kk < 2; ++kk){
            int cc = ccol[kk];
            bfrag a[4];
#pragma unroll
            for (int m = 0; m < 4; ++m)
                a[m] = *reinterpret_cast<const bfrag*>(&As[(wm*64 + m*16 + l15)*64 + cc]);
#pragma unroll
            for (int n = 0; n < 2; ++n){
                bfrag b1 = *reinterpret_cast<const bfrag*>(&B1s[(wn*32 + n*16 + l15)*64 + cc]);
                bfrag b3 = *reinterpret_cast<const bfrag*>(&B3s[(wn*32 + n*16 + l15)*64 + cc]);
#pragma unroll
                for (int m = 0; m < 4; ++m){
                    acc_h[m][n] = __builtin_amdgcn_mfma_f32_16x16x32_bf16(a[m], b1, acc_h[m][n], 0, 0, 0);
                    acc_u[m][n] = __builtin_amdgcn_mfma_f32_16x16x32_bf16(a[m], b3, acc_u[m][n], 0, 0, 0);
                }
            }
        }
        __builtin_amdgcn_s_setprio(0);
    };

    const int NT = HID / 64;   // 16 (even)
    stageT(As0, B10, B30, 0);
    stageT(As1, B11, B31, 1);
#pragma unroll 1
    for (int t = 0; t < NT - 2; t += 2){
        BAR_VM8();                       // stage(t) landed; stage(t+1) in flight
        computeT(As0, B10, B30);
        BAR_PLAIN();                     // all waves done reading buf0
        stageT(As0, B10, B30, t + 2);
        BAR_VM8();                       // stage(t+1) landed; stage(t+2) in flight
        computeT(As1, B11, B31);
        BAR_PLAIN();
        stageT(As1, B11, B31, t + 3);
    }
    BAR_VM8();
    computeT(As0, B10, B30);             // tile NT-2
    BAR_VM0();
    computeT(As1, B11, B31);             // tile NT-1

    // epilogue: act = pair_w * silu(h) * u  (bf16)
    size_t arow0 = (size_t)(by * 128) * INTER;
#pragma unroll
    for (int m = 0; m < 4; ++m){
#pragma unroll
        for (int n = 0; n < 2; ++n){
#pragma unroll
            for (int j = 0; j < 4; ++j){
                int rl = wm*64 + m*16 + (lane >> 4)*4 + j;
                float h = acc_h[m][n][j];
                float u = acc_u[m][n][j];
                float v = pws[rl] * h * u / (1.f + __expf(-h));
                int ic = icol0 + wn*32 + n*16 + l15;
                act[arow0 + (size_t)rl * INTER + ic] = f2bf(v);
            }
        }
    }
}

// ---------------- down-proj GEMM: out[tok,:] += act[row,:] @ w2[e]^T ----------------
// M 128 x N 128, BK=64, K=INTER, double-buffered, counted vmcnt, swizzled LDS,
// L2 supertile: 4 M-tiles resident across the 8 h-panels  [round-8 proven structure]
__global__ __launch_bounds__(256) void gemm2_kernel(
    const unsigned short* __restrict__ act,
    const unsigned short* __restrict__ w2b,
    const int* __restrict__ offp,
    const int* __restrict__ pair_token,
    float* __restrict__ out, int r0)
{
    int nP = gridDim.x, nM = gridDim.y;
    int sw = xcd_swz(blockIdx.y * nP + blockIdx.x, nP * nM);
    int mt, p;
    st_decode(sw, nM, nP, 4, mt, p);
    int by = mt, bx = p;

    int R = r0 + by * 128;
    if (R >= offp[NEXP]) return;
    int e = 0;
    while (offp[e+1] <= R) ++e;
    int h0 = bx * 128;

    __shared__ alignas(16) unsigned short As0[128*64], As1[128*64];
    __shared__ alignas(16) unsigned short Bs0[128*64], Bs1[128*64];
    __shared__ int toks[128];

    int tid = threadIdx.x;
    if (tid < 128) toks[tid] = pair_token[R + tid];
    __syncthreads();

    int w = tid >> 6, lane = tid & 63;
    int wm = w >> 1, wn = w & 1;
    int lr = lane >> 3;
    int l15 = lane & 15;
    int swz8 = ((lane & 7) ^ lr) * 8;

    const unsigned short* w2e = w2b + (size_t)e * HID * INTER;
    size_t arow0 = (size_t)(by * 128) * INTER;

    size_t asrc[4], bsrc[4];
#pragma unroll
    for (int i = 0; i < 4; ++i){
        asrc[i] = arow0 + (size_t)(w*32 + i*8 + lr) * INTER + swz8;
        bsrc[i] = (size_t)(h0 + w*32 + i*8 + lr) * INTER + swz8;
    }

    int ccol[2];
#pragma unroll
    for (int kk = 0; kk < 2; ++kk)
        ccol[kk] = (((kk*4 + (lane >> 4)) ^ (lane & 7)) * 8);

    f32x4 acc[4][4];
#pragma unroll
    for (int m = 0; m < 4; ++m)
#pragma unroll
        for (int n = 0; n < 4; ++n)
            acc[m][n] = (f32x4){0.f,0.f,0.f,0.f};

    // exactly 8 gload16 per thread per stage
    auto stageT = [&](unsigned short* As, unsigned short* Bs, int t){
        int kc = t * 64;
#pragma unroll
        for (int i = 0; i < 4; ++i) gload16(act + asrc[i] + kc, As + (w*32 + i*8)*64);
#pragma unroll
        for (int i = 0; i < 4; ++i) gload16(w2e + bsrc[i] + kc, Bs + (w*32 + i*8)*64);
    };

    auto computeT = [&](const unsigned short* As, const unsigned short* Bs){
        __builtin_amdgcn_s_setprio(1);
#pragma unroll
        for (int kk = 0; kk < 2; ++kk){
            int cc = ccol[kk];
            bfrag a[4];
#pragma unroll
            for (int m = 0; m < 4; ++m)
                a[m] = *reinterpret_cast<const bfrag*>(&As[(wm*64 + m*16 + l15)*64 + cc]);
#pragma unroll
            for (int n = 0; n < 4; ++n){
                bfrag b = *reinterpret_cast<const bfrag*>(&Bs[(wn*64 + n*16 + l15)*64 + cc]);
#pragma unroll
                for (int m = 0; m < 4; ++m)
                    acc[m][n] = __builtin_amdgcn_mfma_f32_16x16x32_bf16(a[m], b, acc[m][n], 0, 0, 0);
            }
        }
        __builtin_amdgcn_s_setprio(0);
    };

    const int NT = INTER / 64;   // 56 (even)
    stageT(As0, Bs0, 0);
    stageT(As1, Bs1, 1);
#pragma unroll 1
    for (int t = 0; t < NT - 2; t += 2){
        BAR_VM8();
        computeT(As0, Bs0);
        BAR_PLAIN();
        stageT(As0, Bs0, t + 2);
        BAR_VM8();
        computeT(As1, Bs1);
        BAR_PLAIN();
        stageT(As1, Bs1, t + 3);
    }
    BAR_VM8();
    computeT(As0, Bs0);
    BAR_VM0();
    computeT(As1, Bs1);

#pragma unroll
    for (int m = 0; m < 4; ++m){
#pragma unroll
        for (int n = 0; n < 4; ++n){
#pragma unroll
            for (int j = 0; j < 4; ++j){
                int rl = wm*64 + m*16 + (lane >> 4)*4 + j;
                int hc = h0 + wn*64 + n*16 + l15;
                atomicAdd(&out[(size_t)toks[rl] * HID + hc], acc[m][n][j]);
            }
        }
    }
}

extern "C" void kernel_launch(void* const* d_in, const int* in_sizes, int n_in,
                              void* d_out, int out_size, void* d_ws, size_t ws_size,
                              hipStream_t stream)
{
    const float* x  = (const float*)d_in[0];
    const float* gw = (const float*)d_in[1];
    const float* w1 = (const float*)d_in[2];
    const float* w3 = (const float*)d_in[3];
    const float* w2 = (const float*)d_in[4];
    float* out = (float*)d_out;

    char* ws = (char*)d_ws;
    size_t off = 0;
    auto bump = [&](size_t bytes) -> void* {
        void* p = ws + off;
        off = (off + bytes + 255) & ~(size_t)255;
        return p;
    };
    int*   counts     = (int*)bump(32);
    int*   cursors    = (int*)bump(32);
    int*   offp       = (int*)bump(64);
    int*   topk_idx   = (int*)bump((size_t)PAIRS * 4);
    float* topk_w     = (float*)bump((size_t)PAIRS * 4);
    int*   pair_token = (int*)bump((size_t)PAD_MAX * 4);
    float* pair_w     = (float*)bump((size_t)PAD_MAX * 4);
    unsigned short* xb  = (unsigned short*)bump((size_t)T_TOKENS * HID * 2);
    unsigned short* w1b = (unsigned short*)bump((size_t)NEXP * INTER * HID * 2);
    unsigned short* w3b = (unsigned short*)bump((size_t)NEXP * INTER * HID * 2);
    unsigned short* w2b = (unsigned short*)bump((size_t)NEXP * HID * INTER * 2);
    unsigned short* act = (unsigned short*)(ws + off);

    size_t rem = (ws_size > off) ? (ws_size - off) : 0;
    int RC = (int)(rem / ((size_t)INTER * 2));
    RC &= ~127;
    if (RC > PAD_MAX) RC = PAD_MAX;
    if (RC < 128) RC = 128;
    int nchunks = (PAD_MAX + RC - 1) / RC;

    hipMemsetAsync(d_out, 0, (size_t)T_TOKENS * HID * 4, stream);
    hipMemsetAsync(ws, 0, 1024, stream);

    conv3_kernel<<<dim3(768, 3), 256, 0, stream>>>(w1, w3, w2, w1b, w3b, w2b);

    router_kernel<<<T_TOKENS/4, 256, 0, stream>>>(x, gw, topk_idx, topk_w, xb);
    hist_kernel<<<64, 256, 0, stream>>>(topk_idx, counts);
    scan_kernel<<<1, 64, 0, stream>>>(counts, offp);
    padfill_kernel<<<NEXP, 128, 0, stream>>>(counts, offp, pair_token, pair_w);
    scatter_kernel<<<T_TOKENS/256, 256, 0, stream>>>(topk_idx, topk_w, offp, cursors,
                                                     pair_token, pair_w);

    for (int c = 0; c < nchunks; ++c){
        int r0 = c * RC;
        gemm_act_kernel<<<dim3(INTER/64, RC/128), 256, 0, stream>>>(
            xb, w1b, w3b, offp, pair_token, pair_w, act, r0);
        gemm2_kernel<<<dim3(HID/128, RC/128), 256, 0, stream>>>(
            act, w2b, offp, pair_token, out, r0);
    }
}